// Round 9
// baseline (3513.535 us; speedup 1.0000x reference)
//
#include <hip/hip_runtime.h>
#include <hip/hip_fp16.h>
#include <math.h>

#define NN 100000
#define NE 3200000
#define NHEAD 4
#define HC 32
#define NG 512
#define EDGES (NE + NN)                 // 3,300,000

#define G1BLKS (NN / 8)                 // 12500

// ---- counting-sort CSR params ----
#define BKT_BITS 9
#define BKT_SIZE 512                    // nodes per pass-1 bucket
#define NBKT 196                        // ceil(NN/512)
#define CHUNK1 16384
#define NB1 ((EDGES + CHUNK1 - 1) / CHUNK1)   // 202
#define NB1S 204                        // padded row stride for CmatT
#define CAP2 18432                      // staging cap (mean 16837, std ~130)
#define SBINS 1792                      // src>>6 bins (1568) padded
#define NBIN2 (4 * SBINS)               // 7168 = 4 sub-buckets x src-bins
#define BPT 7                           // bins per thread (7168/1024)
#define NAGG 784                        // 128-node agg buckets
#define PCHUNK 128

__device__ __forceinline__ float lrelu(float x) { return x > 0.f ? x : 0.2f * x; }

// ---------------- layer-1 GEMM (K=128), h stored fp16 ----------------
__global__ __launch_bounds__(256) void gemm1(
    const float* __restrict__ x, const float* __restrict__ W1,
    const float* __restrict__ as1, const float* __restrict__ ad1,
    __half* __restrict__ h, float* __restrict__ als, float* __restrict__ ald) {
    __shared__ float Wl[128 * HC];
    __shared__ float xl[8][128];
    int tid = threadIdx.x;
    for (int i = tid; i < 128 * HC; i += 256) Wl[i] = W1[i];
    int n0 = blockIdx.x * 8;
    {
        float4 v = *reinterpret_cast<const float4*>(x + n0 * 128 + tid * 4);
        int idx = tid * 4;
        int r = idx >> 7, c = idx & 127;
        *reinterpret_cast<float4*>(&xl[r][c]) = v;
    }
    __syncthreads();
    int r = tid >> 5, col = tid & 31;
    int n = n0 + r;
    float acc = 0.f;
#pragma unroll
    for (int k = 0; k < 128; ++k) acc = fmaf(xl[r][k], Wl[k * HC + col], acc);
    float s = acc * as1[col];
    float d = acc * ad1[col];
#pragma unroll
    for (int off = 1; off < 8; off <<= 1) {
        s += __shfl_xor(s, off);
        d += __shfl_xor(d, off);
    }
    h[n * HC + col] = __float2half(acc);
    if ((col & 7) == 0) {
        als[n * NHEAD + (col >> 3)] = s;
        ald[n * NHEAD + (col >> 3)] = d;
    }
}

// ---------------- CSR pass 1: bucket histogram (transposed count matrix) ----------
__global__ __launch_bounds__(512) void pass1_hist(const int* __restrict__ ei,
                                                  int* __restrict__ CmatT) {
    __shared__ int hcnt[NBKT];
    for (int i = threadIdx.x; i < NBKT; i += 512) hcnt[i] = 0;
    __syncthreads();
    int base = blockIdx.x * CHUNK1;
    int lim = min(base + CHUNK1, EDGES);
    for (int e = base + threadIdx.x; e < lim; e += 512) {
        int dst = (e < NE) ? ei[NE + e] : (e - NE);
        atomicAdd(&hcnt[dst >> BKT_BITS], 1);
    }
    __syncthreads();
    for (int i = threadIdx.x; i < NBKT; i += 512)
        CmatT[i * NB1S + blockIdx.x] = hcnt[i];
}

// one wave per bucket: exclusive scan of the 202 per-block counts
__global__ __launch_bounds__(64) void colscan2(int* __restrict__ CmatT,
                                               int* __restrict__ degTot) {
    int k = blockIdx.x;
    int lane = threadIdx.x;
    int* p = CmatT + k * NB1S;
    int i0 = lane * 4;
    int v0 = (i0 + 0 < NB1) ? p[i0 + 0] : 0;
    int v1 = (i0 + 1 < NB1) ? p[i0 + 1] : 0;
    int v2 = (i0 + 2 < NB1) ? p[i0 + 2] : 0;
    int v3 = (i0 + 3 < NB1) ? p[i0 + 3] : 0;
    int e1 = v0, e2 = v0 + v1, e3 = v0 + v1 + v2;
    int tot = e3 + v3;
    int run = tot;
#pragma unroll
    for (int off = 1; off < 64; off <<= 1) {
        int u = __shfl_up(run, off);
        if (lane >= off) run += u;
    }
    int excl = run - tot;
    if (i0 + 0 < NB1) p[i0 + 0] = excl;
    if (i0 + 1 < NB1) p[i0 + 1] = excl + e1;
    if (i0 + 2 < NB1) p[i0 + 2] = excl + e2;
    if (i0 + 3 < NB1) p[i0 + 3] = excl + e3;
    if (lane == 63) degTot[k] = run;
}

__global__ __launch_bounds__(256) void bucket_apex(const int* __restrict__ degTot,
                                                   int* __restrict__ bucketStart) {
    __shared__ int tot[256];
    int k = threadIdx.x;
    int own = (k < NBKT) ? degTot[k] : 0;
    tot[k] = own;
    __syncthreads();
    for (int off = 1; off < 256; off <<= 1) {
        int u = (k >= off) ? tot[k - off] : 0;
        __syncthreads();
        tot[k] += u;
        __syncthreads();
    }
    if (k < NBKT) bucketStart[k] = tot[k] - own;
    if (k == 255) bucketStart[NBKT] = tot[255];
}

// pass 1 scatter: dense per-(block,bucket) runs of packed (dstLow9<<20 | src)
__global__ __launch_bounds__(512) void pass1_scatter(const int* __restrict__ ei,
                                                     const int* __restrict__ CmatT,
                                                     const int* __restrict__ bucketStart,
                                                     unsigned int* __restrict__ ebuf) {
    __shared__ int cur[NBKT];
    for (int i = threadIdx.x; i < NBKT; i += 512)
        cur[i] = bucketStart[i] + CmatT[i * NB1S + blockIdx.x];
    __syncthreads();
    int base = blockIdx.x * CHUNK1;
    int lim = min(base + CHUNK1, EDGES);
    for (int e = base + threadIdx.x; e < lim; e += 512) {
        int src, dst;
        if (e < NE) { src = ei[e]; dst = ei[NE + e]; }
        else        { src = dst = e - NE; }
        int pos = atomicAdd(&cur[dst >> BKT_BITS], 1);
        ebuf[pos] = ((unsigned int)(dst & (BKT_SIZE - 1)) << 20) | (unsigned int)src;
    }
}

// pass 2: per-512-bucket counting sort by (128-sub-bucket, src>>6).
// Result: edges grouped by 128-node agg bucket, src-MONOTONE within.
__global__ __launch_bounds__(1024) void pass2_sort(const unsigned int* __restrict__ ebuf,
                                                   const int* __restrict__ bucketStart,
                                                   unsigned int* __restrict__ csr,
                                                   int* __restrict__ bs128) {
    __shared__ int hist[NBIN2];
    __shared__ int psum[1024];
    __shared__ unsigned int staging[CAP2];
    int t = threadIdx.x;
    int k = blockIdx.x;
    int start = bucketStart[k], end = bucketStart[k + 1];
    int count = end - start;
    for (int i = t; i < NBIN2; i += 1024) hist[i] = 0;
    __syncthreads();
    for (int i = start + t; i < end; i += 1024) {
        unsigned int v = ebuf[i];
        int src = (int)(v & 0xFFFFFu);
        int sub = (int)((v >> 27) & 3u);          // dst bits [8:7]
        atomicAdd(&hist[sub * SBINS + (src >> 6)], 1);
    }
    __syncthreads();
    int base = t * BPT;
    int loc[BPT];
    int s = 0;
#pragma unroll
    for (int j = 0; j < BPT; ++j) { loc[j] = s; s += hist[base + j]; }
    psum[t] = s;
    __syncthreads();
    for (int off = 1; off < 1024; off <<= 1) {
        int u = (t >= off) ? psum[t - off] : 0;
        __syncthreads();
        psum[t] += u;
        __syncthreads();
    }
    int ex = psum[t] - s;
#pragma unroll
    for (int j = 0; j < BPT; ++j) loc[j] += ex;
    // sub-bucket boundaries land exactly on threads 0,256,512,768 (1792 = 256*7)
    if ((t & 255) == 0) bs128[k * 4 + (t >> 8)] = start + loc[0];
    if (k == NBKT - 1 && t == 0) bs128[NAGG] = end;
#pragma unroll
    for (int j = 0; j < BPT; ++j) hist[base + j] = loc[j];   // cursors (bucket-rel)
    __syncthreads();
    for (int i = start + t; i < end; i += 1024) {
        unsigned int v = ebuf[i];
        int src = (int)(v & 0xFFFFFu);
        int sub = (int)((v >> 27) & 3u);
        int pos = atomicAdd(&hist[sub * SBINS + (src >> 6)], 1);
        if (pos < CAP2) staging[pos] = v;
    }
    __syncthreads();
    for (int i = t; i < count; i += 1024) csr[start + i] = staging[i];
}

// ---------------- src-streaming GAT aggregation (scatter-to-LDS) ----------------
// One block per 128-node dst bucket; output accumulators live in LDS.
// Edge list is src-sorted -> h[src] reads are a monotone sweep shared (via L2)
// across all co-resident blocks. No global gather misses, no partial-acc buffers.
template<bool FUSE>
__global__ __launch_bounds__(256) void agg_bucket(
    const unsigned int* __restrict__ csr, const int* __restrict__ bs128,
    const float* __restrict__ als, const float* __restrict__ ald,
    const __half* __restrict__ h, const float* __restrict__ bias,
    const float* __restrict__ Wn, const float* __restrict__ asn,
    const float* __restrict__ adn,
    __half* __restrict__ h_out, float* __restrict__ als_out,
    float* __restrict__ ald_out, float* __restrict__ act_out) {
    __shared__ float accL[128 * HC];     // 16 KB, bank = lane (conflict-free)
    __shared__ float denL[128 * NHEAD];  // 2 KB
    __shared__ float Wl[HC * HC];        // 4 KB (FUSE)
    int tid = threadIdx.x;
    int b = blockIdx.x;
    for (int i = tid; i < 128 * HC; i += 256) accL[i] = 0.f;
    for (int i = tid; i < 128 * NHEAD; i += 256) denL[i] = 0.f;
    if (FUSE)
        for (int i = tid; i < HC * HC; i += 256) Wl[i] = Wn[i];
    __syncthreads();

    int start = bs128[b], end = bs128[b + 1];
    int lane = tid & 31;
    int head = lane >> 3;
    int slot = lane & 7;
    int gid = tid >> 5;                  // 8 groups x 8 edges = 64-edge superchunk
    const __half* hL = h + lane;
    int dbase = b * 128;

    for (int c0 = start + gid * 8; c0 < end; c0 += 64) {
        int e = c0 + slot;
        bool ok = (e < end);
        unsigned int v = ok ? __builtin_nontemporal_load(csr + e) : 0u;
        int s = (int)(v & 0xFFFFFu);
        int dl = (int)((v >> 20) & 127u);
        float p = __expf(lrelu(als[s * NHEAD + head] + ald[(dbase + dl) * NHEAD + head]));
        p = ok ? p : 0.f;
        atomicAdd(&denL[dl * NHEAD + head], p);
#pragma unroll
        for (int j = 0; j < 8; ++j) {
            unsigned int vj = __shfl(v, j, 32);
            int sj = (int)(vj & 0xFFFFFu);
            int dlj = (int)((vj >> 20) & 127u);
            float pj = __shfl(p, (lane & 24) | j, 32);
            float hv = __half2float(hL[sj * HC]);
            atomicAdd(&accL[dlj * HC + lane], pj * hv);
        }
    }
    __syncthreads();

    // epilogue: normalize + bias + ELU (+ fused next-layer GEMM)
    for (int i = 0; i < 16; ++i) {
        int nl = gid * 16 + i;
        int n = dbase + nl;
        if (n >= NN) break;
        float den = denL[nl * NHEAD + head];
        float v = accL[nl * HC + lane] / den + bias[lane];
        float av = v > 0.f ? v : (__expf(v) - 1.f);
        if (!FUSE) {
            act_out[n * HC + lane] = av;
        } else {
            float hacc = 0.f;
#pragma unroll
            for (int kk = 0; kk < HC; ++kk)
                hacc = fmaf(__shfl(av, kk, 32), Wl[kk * HC + lane], hacc);
            h_out[n * HC + lane] = __float2half(hacc);
            float sv = hacc * asn[lane];
            float dv = hacc * adn[lane];
#pragma unroll
            for (int off = 1; off < 8; off <<= 1) {
                sv += __shfl_xor(sv, off);
                dv += __shfl_xor(dv, off);
            }
            if ((lane & 7) == 0) {
                als_out[n * NHEAD + head] = sv;
                ald_out[n * NHEAD + head] = dv;
            }
        }
    }
}

// ---------------- pooling (sorted batch) + FC ----------------
__global__ void pool_init(float* __restrict__ sums, float* __restrict__ cnt) {
    int i = blockIdx.x * blockDim.x + threadIdx.x;
    if (i < NG * HC) sums[i] = 0.f;
    if (i < NG) cnt[i] = 0.f;
}

__global__ __launch_bounds__(256) void pool_seg(const float* __restrict__ act,
                                                const int* __restrict__ batch,
                                                float* __restrict__ sums,
                                                float* __restrict__ cnt) {
    int grp = blockIdx.x * 8 + (threadIdx.x >> 5);
    int lane = threadIdx.x & 31;
    int n0 = grp * PCHUNK;
    if (n0 >= NN) return;
    int n1 = min(n0 + PCHUNK, NN);
    int curg = batch[n0];
    float acc = 0.f, c = 0.f;
    for (int n = n0; n < n1; ++n) {
        int gg = batch[n];
        if (gg != curg) {
            atomicAdd(&sums[curg * HC + lane], acc);
            if (lane == 0) atomicAdd(&cnt[curg], c);
            acc = 0.f; c = 0.f; curg = gg;
        }
        acc += act[n * HC + lane];
        c += 1.f;
    }
    atomicAdd(&sums[curg * HC + lane], acc);
    if (lane == 0) atomicAdd(&cnt[curg], c);
}

__global__ void fc_out(const float* __restrict__ sums, const float* __restrict__ cnt,
                       const float* __restrict__ fcw, const float* __restrict__ fcb,
                       float* __restrict__ out) {
    int g = blockIdx.x;
    int lane = threadIdx.x;
    float v = (lane < HC) ? sums[g * HC + lane] * fcw[lane] : 0.f;
#pragma unroll
    for (int off = 32; off; off >>= 1) v += __shfl_down(v, off);
    if (lane == 0) out[g] = v / fmaxf(cnt[g], 1.f) + fcb[0];
}

extern "C" void kernel_launch(void* const* d_in, const int* in_sizes, int n_in,
                              void* d_out, int out_size, void* d_ws, size_t ws_size,
                              hipStream_t stream) {
    const float* x     = (const float*)d_in[0];
    const int*   ei    = (const int*)d_in[1];
    const int*   batch = (const int*)d_in[2];
    const float* W[4]   = {(const float*)d_in[3],  (const float*)d_in[7],
                           (const float*)d_in[11], (const float*)d_in[15]};
    const float* asr[4] = {(const float*)d_in[4],  (const float*)d_in[8],
                           (const float*)d_in[12], (const float*)d_in[16]};
    const float* adt[4] = {(const float*)d_in[5],  (const float*)d_in[9],
                           (const float*)d_in[13], (const float*)d_in[17]};
    const float* bb[4]  = {(const float*)d_in[6],  (const float*)d_in[10],
                           (const float*)d_in[14], (const float*)d_in[18]};
    const float* fcw = (const float*)d_in[19];
    const float* fcb = (const float*)d_in[20];
    float* out = (float*)d_out;

    char* ws = (char*)d_ws;
    size_t off = 0;
    auto carve = [&](size_t bytes) {
        void* p = ws + off;
        off += (bytes + 255) & ~size_t(255);
        return p;
    };
    __half* hA   = (__half*)carve(sizeof(__half) * NN * HC);
    __half* hB   = (__half*)carve(sizeof(__half) * NN * HC);
    float* actF  = (float*)carve(sizeof(float) * NN * HC);
    float* alsA  = (float*)carve(sizeof(float) * NN * NHEAD);
    float* aldA  = (float*)carve(sizeof(float) * NN * NHEAD);
    float* alsB  = (float*)carve(sizeof(float) * NN * NHEAD);
    float* aldB  = (float*)carve(sizeof(float) * NN * NHEAD);
    int*   CmatT = (int*)carve(sizeof(int) * NBKT * NB1S);
    int*   degTot= (int*)carve(sizeof(int) * NBKT);
    int*   bkst  = (int*)carve(sizeof(int) * (NBKT + 1));
    unsigned int* ebuf = (unsigned int*)carve(sizeof(unsigned int) * EDGES);
    int*   bs128 = (int*)carve(sizeof(int) * (NAGG + 1));
    unsigned int* csr  = (unsigned int*)carve(sizeof(unsigned int) * EDGES);
    float* sums  = (float*)carve(sizeof(float) * NG * HC);
    float* cnt   = (float*)carve(sizeof(float) * NG);

    // ---- CSR build: 2-pass counting sort; final order (dst-128-bucket, src) ----
    pass1_hist<<<NB1, 512, 0, stream>>>(ei, CmatT);
    colscan2<<<NBKT, 64, 0, stream>>>(CmatT, degTot);
    bucket_apex<<<1, 256, 0, stream>>>(degTot, bkst);
    pass1_scatter<<<NB1, 512, 0, stream>>>(ei, CmatT, bkst, ebuf);
    pass2_sort<<<NBKT, 1024, 0, stream>>>(ebuf, bkst, csr, bs128);

    // ---- layer-1 GEMM ----
    gemm1<<<G1BLKS, 256, 0, stream>>>(x, W[0], asr[0], adt[0], hA, alsA, aldA);

    // ---- 4 GAT layers: src-streaming scatter-to-LDS agg, fused next GEMM ----
    agg_bucket<true><<<NAGG, 256, 0, stream>>>(csr, bs128, alsA, aldA, hA, bb[0],
                                               W[1], asr[1], adt[1],
                                               hB, alsB, aldB, nullptr);
    agg_bucket<true><<<NAGG, 256, 0, stream>>>(csr, bs128, alsB, aldB, hB, bb[1],
                                               W[2], asr[2], adt[2],
                                               hA, alsA, aldA, nullptr);
    agg_bucket<true><<<NAGG, 256, 0, stream>>>(csr, bs128, alsA, aldA, hA, bb[2],
                                               W[3], asr[3], adt[3],
                                               hB, alsB, aldB, nullptr);
    agg_bucket<false><<<NAGG, 256, 0, stream>>>(csr, bs128, alsB, aldB, hB, bb[3],
                                                nullptr, nullptr, nullptr,
                                                nullptr, nullptr, nullptr, actF);

    // ---- global mean pool + FC ----
    pool_init<<<(NG * HC + 255) / 256, 256, 0, stream>>>(sums, cnt);
    pool_seg<<<((NN + PCHUNK - 1) / PCHUNK + 7) / 8, 256, 0, stream>>>(actF, batch,
                                                                       sums, cnt);
    fc_out<<<NG, 64, 0, stream>>>(sums, cnt, fcw, fcb, out);
}

// Round 10
// 461.690 us; speedup vs baseline: 7.6102x; 7.6102x over previous
//
#include <hip/hip_runtime.h>
#include <hip/hip_fp16.h>
#include <math.h>

#define NN 100000
#define NE 3200000
#define NHEAD 4
#define HC 32
#define NG 512
#define EDGES (NE + NN)                 // 3,300,000

#define G1BLKS (NN / 8)                 // 12500

// ---- counting-sort CSR params ----
#define BKT_BITS 9
#define BKT_SIZE 512                    // nodes per bucket
#define NBKT 196                        // ceil(NN/512); 196*512 = 100352
#define CHUNK1 16384
#define NB1 ((EDGES + CHUNK1 - 1) / CHUNK1)   // 202
#define NB1S 204                        // padded row stride for CmatT
#define CAP2 18432                      // staging cap (mean 16896)
#define PCHUNK 128

__device__ __forceinline__ float lrelu(float x) { return x > 0.f ? x : 0.2f * x; }

// ---------------- layer-1 GEMM (K=128) fused with CSR pass-1 histogram ----------
__global__ __launch_bounds__(256) void gemm1_hist(
    const float* __restrict__ x, const float* __restrict__ W1,
    const float* __restrict__ as1, const float* __restrict__ ad1,
    __half* __restrict__ h, float* __restrict__ als, float* __restrict__ ald,
    const int* __restrict__ ei, int* __restrict__ CmatT) {
    __shared__ float Wl[128 * HC];
    __shared__ float xl[8][128];
    __shared__ int hcnt[NBKT];
    int tid = threadIdx.x;
    if (blockIdx.x >= G1BLKS) {
        // histogram branch: one block per 16K-edge chunk
        int b1 = blockIdx.x - G1BLKS;
        for (int i = tid; i < NBKT; i += 256) hcnt[i] = 0;
        __syncthreads();
        int base = b1 * CHUNK1;
        int lim = min(base + CHUNK1, EDGES);
        for (int e = base + tid; e < lim; e += 256) {
            int dst = (e < NE) ? ei[NE + e] : (e - NE);
            atomicAdd(&hcnt[dst >> BKT_BITS], 1);
        }
        __syncthreads();
        for (int i = tid; i < NBKT; i += 256)
            CmatT[i * NB1S + b1] = hcnt[i];
        return;
    }
    for (int i = tid; i < 128 * HC; i += 256) Wl[i] = W1[i];
    int n0 = blockIdx.x * 8;
    {
        float4 v = *reinterpret_cast<const float4*>(x + n0 * 128 + tid * 4);
        int idx = tid * 4;
        int r = idx >> 7, c = idx & 127;
        *reinterpret_cast<float4*>(&xl[r][c]) = v;
    }
    __syncthreads();
    int r = tid >> 5, col = tid & 31;
    int n = n0 + r;
    float acc = 0.f;
#pragma unroll
    for (int k = 0; k < 128; ++k) acc = fmaf(xl[r][k], Wl[k * HC + col], acc);
    float s = acc * as1[col];
    float d = acc * ad1[col];
#pragma unroll
    for (int off = 1; off < 8; off <<= 1) {
        s += __shfl_xor(s, off);
        d += __shfl_xor(d, off);
    }
    h[n * HC + col] = __float2half(acc);
    if ((col & 7) == 0) {
        als[n * NHEAD + (col >> 3)] = s;
        ald[n * NHEAD + (col >> 3)] = d;
    }
}

// one wave per bucket: exclusive scan of the 202 per-block counts
__global__ __launch_bounds__(64) void colscan2(int* __restrict__ CmatT,
                                               int* __restrict__ degTot) {
    int k = blockIdx.x;
    int lane = threadIdx.x;
    int* p = CmatT + k * NB1S;
    int i0 = lane * 4;
    int v0 = (i0 + 0 < NB1) ? p[i0 + 0] : 0;
    int v1 = (i0 + 1 < NB1) ? p[i0 + 1] : 0;
    int v2 = (i0 + 2 < NB1) ? p[i0 + 2] : 0;
    int v3 = (i0 + 3 < NB1) ? p[i0 + 3] : 0;
    int e1 = v0, e2 = v0 + v1, e3 = v0 + v1 + v2;
    int tot = e3 + v3;
    int run = tot;
#pragma unroll
    for (int off = 1; off < 64; off <<= 1) {
        int u = __shfl_up(run, off);
        if (lane >= off) run += u;
    }
    int excl = run - tot;
    if (i0 + 0 < NB1) p[i0 + 0] = excl;
    if (i0 + 1 < NB1) p[i0 + 1] = excl + e1;
    if (i0 + 2 < NB1) p[i0 + 2] = excl + e2;
    if (i0 + 3 < NB1) p[i0 + 3] = excl + e3;
    if (lane == 63) degTot[k] = run;
}

__global__ __launch_bounds__(256) void bucket_apex(const int* __restrict__ degTot,
                                                   int* __restrict__ bucketStart) {
    __shared__ int tot[256];
    int k = threadIdx.x;
    int own = (k < NBKT) ? degTot[k] : 0;
    tot[k] = own;
    __syncthreads();
    for (int off = 1; off < 256; off <<= 1) {
        int u = (k >= off) ? tot[k - off] : 0;
        __syncthreads();
        tot[k] += u;
        __syncthreads();
    }
    if (k < NBKT) bucketStart[k] = tot[k] - own;
    if (k == 255) bucketStart[NBKT] = tot[255];
}

// pass 1 scatter: dense per-(block,bucket) runs of packed (dstLow<<20 | src)
__global__ __launch_bounds__(512) void pass1_scatter(const int* __restrict__ ei,
                                                     const int* __restrict__ CmatT,
                                                     const int* __restrict__ bucketStart,
                                                     unsigned int* __restrict__ ebuf) {
    __shared__ int cur[NBKT];
    for (int i = threadIdx.x; i < NBKT; i += 512)
        cur[i] = bucketStart[i] + CmatT[i * NB1S + blockIdx.x];
    __syncthreads();
    int base = blockIdx.x * CHUNK1;
    int lim = min(base + CHUNK1, EDGES);
    for (int e = base + threadIdx.x; e < lim; e += 512) {
        int src, dst;
        if (e < NE) { src = ei[e]; dst = ei[NE + e]; }
        else        { src = dst = e - NE; }
        int pos = atomicAdd(&cur[dst >> BKT_BITS], 1);
        ebuf[pos] = ((unsigned int)(dst & (BKT_SIZE - 1)) << 20) | (unsigned int)src;
    }
}

// pass 2: per-bucket LDS counting sort by dstLow -> dense csrsrc + rowst writes
__global__ __launch_bounds__(1024) void pass2_sort(const unsigned int* __restrict__ ebuf,
                                                   const int* __restrict__ bucketStart,
                                                   int* __restrict__ csrsrc,
                                                   int* __restrict__ rowst) {
    __shared__ int hist[BKT_SIZE];
    __shared__ int scn[BKT_SIZE];
    __shared__ int staging[CAP2];
    int t = threadIdx.x;
    int k = blockIdx.x;
    int start = bucketStart[k], end = bucketStart[k + 1];
    int count = end - start;
    if (t < BKT_SIZE) hist[t] = 0;
    __syncthreads();
    for (int i = start + t; i < end; i += 1024)
        atomicAdd(&hist[ebuf[i] >> 20], 1);
    __syncthreads();
    if (t < BKT_SIZE) scn[t] = hist[t];
    __syncthreads();
    for (int off = 1; off < BKT_SIZE; off <<= 1) {
        int u = (t < BKT_SIZE && t >= off) ? scn[t - off] : 0;
        __syncthreads();
        if (t < BKT_SIZE) scn[t] += u;
        __syncthreads();
    }
    if (t < BKT_SIZE) {
        int ex = scn[t] - hist[t];
        rowst[k * BKT_SIZE + t] = start + ex;
        hist[t] = ex;                       // becomes cursor
    }
    __syncthreads();
    for (int i = start + t; i < end; i += 1024) {
        unsigned int v = ebuf[i];
        int pos = atomicAdd(&hist[v >> 20], 1);
        if (pos < CAP2) staging[pos] = (int)(v & 0xFFFFFu);
    }
    __syncthreads();
    for (int i = t; i < count; i += 1024) csrsrc[start + i] = staging[i];
}

// ---------------- lane-split single-pass GAT aggregation ----------------
// 8-edge chunks; lane (head*8+slot) computes p for edge `slot`, head `head`.
// Software pipeline: next chunk's csrsrc word and als value are loaded during
// the current chunk's exp + 8 gathers (hides the dependent csr->als latency).
template<bool FUSE>
__global__ __launch_bounds__(256) void agg_layer(
    const int* __restrict__ rowst, const int* __restrict__ csrsrc,
    const float* __restrict__ als, const float* __restrict__ ald,
    const __half* __restrict__ h, const float* __restrict__ bias,
    const float* __restrict__ Wn, const float* __restrict__ asn,
    const float* __restrict__ adn,
    __half* __restrict__ h_out, float* __restrict__ als_out,
    float* __restrict__ ald_out, float* __restrict__ act_out) {
    __shared__ float Wl[HC * HC];
    int tid = threadIdx.x;
    if (FUSE) {
        for (int i = tid; i < HC * HC; i += 256) Wl[i] = Wn[i];
        __syncthreads();
    }
    int g = blockIdx.x * 8 + (tid >> 5);
    int lane = tid & 31;
    int head = lane >> 3;
    int slot = lane & 7;
    float adh = ald[g * NHEAD + head];
    int beg = rowst[g], end = rowst[g + 1];

    float acc[8];
#pragma unroll
    for (int j = 0; j < 8; ++j) acc[j] = 0.f;
    float dsum = 0.f;
    const __half* hL = h + lane;

    // pipeline prologue: first chunk's src + als
    int e0 = beg + slot;
    int sP = (e0 < end) ? __builtin_nontemporal_load(csrsrc + e0) : 0;
    float aP = als[sP * NHEAD + head];

    for (int c0 = beg; c0 < end; c0 += 8) {
        // prefetch next chunk
        int eN = c0 + 8 + slot;
        int sN = (eN < end) ? __builtin_nontemporal_load(csrsrc + eN) : 0;
        float aN = als[sN * NHEAD + head];
        // current chunk compute
        bool ok = (c0 + slot) < end;
        float p = __expf(lrelu(aP + adh));
        p = ok ? p : 0.f;
        dsum += p;
#pragma unroll
        for (int j = 0; j < 8; ++j) {
            float pj = __shfl(p, (head << 3) | j, 32);
            int sj = __shfl(sP, j, 32);
            acc[j] = fmaf(pj, __half2float(hL[sj * HC]), acc[j]);
        }
        sP = sN;
        aP = aN;
    }
    float a = ((acc[0] + acc[1]) + (acc[2] + acc[3])) +
              ((acc[4] + acc[5]) + (acc[6] + acc[7]));
    dsum += __shfl_xor(dsum, 1, 32);
    dsum += __shfl_xor(dsum, 2, 32);
    dsum += __shfl_xor(dsum, 4, 32);

    float v = a / dsum + bias[lane];
    float av = v > 0.f ? v : (__expf(v) - 1.f);
    if (!FUSE) {
        act_out[g * HC + lane] = av;
        return;
    }
    float hacc = 0.f;
#pragma unroll
    for (int kk = 0; kk < HC; ++kk)
        hacc = fmaf(__shfl(av, kk, 32), Wl[kk * HC + lane], hacc);
    h_out[g * HC + lane] = __float2half(hacc);
    float sv = hacc * asn[lane];
    float dv = hacc * adn[lane];
#pragma unroll
    for (int off = 1; off < 8; off <<= 1) {
        sv += __shfl_xor(sv, off);
        dv += __shfl_xor(dv, off);
    }
    if ((lane & 7) == 0) {
        als_out[g * NHEAD + head] = sv;
        ald_out[g * NHEAD + head] = dv;
    }
}

// ---------------- pooling (sorted batch) + FC ----------------
__global__ void pool_init(float* __restrict__ sums, float* __restrict__ cnt) {
    int i = blockIdx.x * blockDim.x + threadIdx.x;
    if (i < NG * HC) sums[i] = 0.f;
    if (i < NG) cnt[i] = 0.f;
}

__global__ __launch_bounds__(256) void pool_seg(const float* __restrict__ act,
                                                const int* __restrict__ batch,
                                                float* __restrict__ sums,
                                                float* __restrict__ cnt) {
    int grp = blockIdx.x * 8 + (threadIdx.x >> 5);
    int lane = threadIdx.x & 31;
    int n0 = grp * PCHUNK;
    if (n0 >= NN) return;
    int n1 = min(n0 + PCHUNK, NN);
    int curg = batch[n0];
    float acc = 0.f, c = 0.f;
    for (int n = n0; n < n1; ++n) {
        int gg = batch[n];
        if (gg != curg) {
            atomicAdd(&sums[curg * HC + lane], acc);
            if (lane == 0) atomicAdd(&cnt[curg], c);
            acc = 0.f; c = 0.f; curg = gg;
        }
        acc += act[n * HC + lane];
        c += 1.f;
    }
    atomicAdd(&sums[curg * HC + lane], acc);
    if (lane == 0) atomicAdd(&cnt[curg], c);
}

__global__ void fc_out(const float* __restrict__ sums, const float* __restrict__ cnt,
                       const float* __restrict__ fcw, const float* __restrict__ fcb,
                       float* __restrict__ out) {
    int g = blockIdx.x;
    int lane = threadIdx.x;
    float v = (lane < HC) ? sums[g * HC + lane] * fcw[lane] : 0.f;
#pragma unroll
    for (int off = 32; off; off >>= 1) v += __shfl_down(v, off);
    if (lane == 0) out[g] = v / fmaxf(cnt[g], 1.f) + fcb[0];
}

extern "C" void kernel_launch(void* const* d_in, const int* in_sizes, int n_in,
                              void* d_out, int out_size, void* d_ws, size_t ws_size,
                              hipStream_t stream) {
    const float* x     = (const float*)d_in[0];
    const int*   ei    = (const int*)d_in[1];
    const int*   batch = (const int*)d_in[2];
    const float* W[4]   = {(const float*)d_in[3],  (const float*)d_in[7],
                           (const float*)d_in[11], (const float*)d_in[15]};
    const float* asr[4] = {(const float*)d_in[4],  (const float*)d_in[8],
                           (const float*)d_in[12], (const float*)d_in[16]};
    const float* adt[4] = {(const float*)d_in[5],  (const float*)d_in[9],
                           (const float*)d_in[13], (const float*)d_in[17]};
    const float* bb[4]  = {(const float*)d_in[6],  (const float*)d_in[10],
                           (const float*)d_in[14], (const float*)d_in[18]};
    const float* fcw = (const float*)d_in[19];
    const float* fcb = (const float*)d_in[20];
    float* out = (float*)d_out;

    char* ws = (char*)d_ws;
    size_t off = 0;
    auto carve = [&](size_t bytes) {
        void* p = ws + off;
        off += (bytes + 255) & ~size_t(255);
        return p;
    };
    __half* hA   = (__half*)carve(sizeof(__half) * NN * HC);
    __half* hB   = (__half*)carve(sizeof(__half) * NN * HC);
    float* actF  = (float*)carve(sizeof(float) * NN * HC);
    float* alsA  = (float*)carve(sizeof(float) * NN * NHEAD);
    float* aldA  = (float*)carve(sizeof(float) * NN * NHEAD);
    float* alsB  = (float*)carve(sizeof(float) * NN * NHEAD);
    float* aldB  = (float*)carve(sizeof(float) * NN * NHEAD);
    int*   CmatT = (int*)carve(sizeof(int) * NBKT * NB1S);
    int*   degTot= (int*)carve(sizeof(int) * NBKT);
    int*   bkst  = (int*)carve(sizeof(int) * (NBKT + 1));
    unsigned int* ebuf = (unsigned int*)carve(sizeof(unsigned int) * EDGES);
    int*   rowst = (int*)carve(sizeof(int) * NBKT * BKT_SIZE);
    int*   csrsrc= (int*)carve(sizeof(int) * EDGES);
    float* sums  = (float*)carve(sizeof(float) * NG * HC);
    float* cnt   = (float*)carve(sizeof(float) * NG);

    // ---- layer-1 GEMM fused with CSR pass-1 histogram (independent work) ----
    gemm1_hist<<<G1BLKS + NB1, 256, 0, stream>>>(x, W[0], asr[0], adt[0],
                                                 hA, alsA, aldA, ei, CmatT);
    // ---- CSR build rest ----
    colscan2<<<NBKT, 64, 0, stream>>>(CmatT, degTot);
    bucket_apex<<<1, 256, 0, stream>>>(degTot, bkst);
    pass1_scatter<<<NB1, 512, 0, stream>>>(ei, CmatT, bkst, ebuf);
    pass2_sort<<<NBKT, 1024, 0, stream>>>(ebuf, bkst, csrsrc, rowst);

    // ---- 4 GAT layers: agg(L) fused with gemm(L+1) ----
    agg_layer<true><<<G1BLKS, 256, 0, stream>>>(rowst, csrsrc, alsA, aldA, hA, bb[0],
                                                W[1], asr[1], adt[1],
                                                hB, alsB, aldB, nullptr);
    agg_layer<true><<<G1BLKS, 256, 0, stream>>>(rowst, csrsrc, alsB, aldB, hB, bb[1],
                                                W[2], asr[2], adt[2],
                                                hA, alsA, aldA, nullptr);
    agg_layer<true><<<G1BLKS, 256, 0, stream>>>(rowst, csrsrc, alsA, aldA, hA, bb[2],
                                                W[3], asr[3], adt[3],
                                                hB, alsB, aldB, nullptr);
    agg_layer<false><<<G1BLKS, 256, 0, stream>>>(rowst, csrsrc, alsB, aldB, hB, bb[3],
                                                 nullptr, nullptr, nullptr,
                                                 nullptr, nullptr, nullptr, actF);

    // ---- global mean pool + FC ----
    pool_init<<<(NG * HC + 255) / 256, 256, 0, stream>>>(sums, cnt);
    pool_seg<<<((NN + PCHUNK - 1) / PCHUNK + 7) / 8, 256, 0, stream>>>(actF, batch,
                                                                       sums, cnt);
    fc_out<<<NG, 64, 0, stream>>>(sums, cnt, fcw, fcb, out);
}